// Round 11
// baseline (4018.179 us; speedup 1.0000x reference)
//
#include <hip/hip_runtime.h>
#include <cstdint>
#include <cstddef>
#include <type_traits>

// LSTM decoder: SEQ=256 steps, BATCH=256, HID=1024, OUT=512. f32 in/out.
// Folded recurrence (Wc2 = W_ih @ W_out): each step is ONE GEMM
//   gates = [h | c] @ [W_hh | Wc2]^T  (M=256, N=4096, K=2048, bf16 MFMA)
// Round-11: LDS removed from the GEMM path. 8-way k-split waves (each wave:
// all 64 gate-cols x 256-k slice); A fragments loaded DIRECT global->VGPR
// (2-kstep software pipeline, compiler-scheduled waits, zero barriers in the
// loop). LDS only holds the 8-way k-reduce dump (128KB). Sync = round-10's
// proven slot-flag + sc1 + early-publish. Weights in registers all 256 steps.
// Scratch lives in the `outs` third of d_out; d_ws unused.

#define SEQ    256
#define BATCH  256
#define HID    1024
#define OUTD   512
#define KDIM   2048
#define GATES  4096

typedef __bf16 bf16x8 __attribute__((ext_vector_type(8)));
typedef float  f32x4  __attribute__((ext_vector_type(4)));

__device__ __forceinline__ unsigned short f2bf(float x) {
  unsigned u = __float_as_uint(x);
  u = (u + 0x7FFFu + ((u >> 16) & 1u)) >> 16;   // RNE
  return (unsigned short)u;
}

__device__ __forceinline__ f32x4 mfma16(bf16x8 a, bf16x8 b, f32x4 c) {
  return __builtin_amdgcn_mfma_f32_16x16x32_bf16(a, b, c, 0, 0, 0);
}

__device__ __forceinline__ bf16x8 ld_frag_bf(const unsigned short* p) {
  uint4 u = *reinterpret_cast<const uint4*>(p);
  return __builtin_bit_cast(bf16x8, u);
}

__device__ __forceinline__ float rcp_fast(float x) {
  float r;
  asm("v_rcp_f32 %0, %1" : "=v"(r) : "v"(x));
  return r;
}
__device__ __forceinline__ float sigmoid_fast(float x) {
  return rcp_fast(1.f + __expf(-x));
}
__device__ __forceinline__ float tanh_fast(float x) {
  float xc = fminf(fmaxf(x, -15.f), 15.f);     // e^{2x} finite; tanh saturated
  float e2 = __expf(2.f * xc);
  return 1.f - 2.f * rcp_fast(1.f + e2);
}

// ---------------- prep kernels ----------------

__global__ void k_cast_whh(const float* __restrict__ whh, unsigned short* __restrict__ wg2) {
  int i4 = blockIdx.x * blockDim.x + threadIdx.x;
  if (i4 >= (GATES * HID) / 4) return;
  int idx = i4 * 4;
  int n = idx >> 10, k = idx & 1023;
  const float4 v = *reinterpret_cast<const float4*>(whh + idx);
  ushort4 o; o.x = f2bf(v.x); o.y = f2bf(v.y); o.z = f2bf(v.z); o.w = f2bf(v.w);
  *reinterpret_cast<ushort4*>(wg2 + (size_t)n * KDIM + k) = o;
}

__global__ void k_cast_wout(const float* __restrict__ wout,
                            unsigned short* __restrict__ wott) {
  int idx = blockIdx.x * blockDim.x + threadIdx.x;
  if (idx >= OUTD * HID) return;
  int j = idx >> 10, k = idx & 1023;
  wott[(size_t)k * OUTD + j] = f2bf(wout[idx]);
}

// A0 = [bf16(c_vector) | 0]; zero the 256 per-WG step flags (every launch,
// for graph-replay determinism).
__global__ void k_init(const float* __restrict__ cvec,
                       unsigned short* __restrict__ a0,
                       unsigned* __restrict__ flags) {
  int idx = blockIdx.x * blockDim.x + threadIdx.x;
  if (idx < 256) flags[idx] = 0u;
  if (idx >= BATCH * KDIM) return;
  int b = idx >> 11, k = idx & 2047;
  a0[idx] = (k < HID) ? f2bf(cvec[(size_t)b * HID + k]) : (unsigned short)0;
}

// bias0[n] = b_ih+b_hh ; bias2[n] = bias0[n] + dot(W_ih[n,:], b_out)
__global__ void k_bias(const float* __restrict__ wih, const float* __restrict__ b_ih,
                       const float* __restrict__ b_hh, const float* __restrict__ b_out,
                       float* __restrict__ bias0, float* __restrict__ bias2) {
  int wave = threadIdx.x >> 6, l = threadIdx.x & 63;
  int n = blockIdx.x * 4 + wave;
  float s = 0.f;
  for (int j = l; j < OUTD; j += 64) s += wih[(size_t)n * OUTD + j] * b_out[j];
  for (int off = 32; off; off >>= 1) s += __shfl_down(s, off);
  if (l == 0) {
    float b0 = b_ih[n] + b_hh[n];
    bias0[n] = b0;
    bias2[n] = b0 + s;
  }
}

// ---------------- generic bf16-MFMA GEMM (unchanged, passing) ----------
template <typename AT>
__device__ __forceinline__ bf16x8 ld_frag(const AT* p) {
  if constexpr (std::is_same_v<AT, float>) {
    const float4 f0 = *reinterpret_cast<const float4*>(p);
    const float4 f1 = *reinterpret_cast<const float4*>(p + 4);
    uint4 v;
    v.x = (unsigned)f2bf(f0.x) | ((unsigned)f2bf(f0.y) << 16);
    v.y = (unsigned)f2bf(f0.z) | ((unsigned)f2bf(f0.w) << 16);
    v.z = (unsigned)f2bf(f1.x) | ((unsigned)f2bf(f1.y) << 16);
    v.w = (unsigned)f2bf(f1.z) | ((unsigned)f2bf(f1.w) << 16);
    return __builtin_bit_cast(bf16x8, v);
  } else {
    return ld_frag_bf(p);
  }
}

template <typename AT, typename BT, typename DT>
__global__ __launch_bounds__(256)
void k_gemm(const AT* __restrict__ A, int lda,
            const BT* __restrict__ Bn, int ldb,
            DT* __restrict__ D, int ldd,
            const float* __restrict__ bias, int K) {
  __shared__ char lds[64 * 1024];
  const int tid = threadIdx.x;
  const int w = tid >> 6, l = tid & 63;
  const int n0 = blockIdx.x * 64;
  const int m0 = blockIdx.y * 64 + w * 16;
  const int lr = l & 15, lg = l >> 4;

  f32x4 acc[4] = {};
  for (int kc = 0; kc < K; kc += 512) {
    __syncthreads();
    for (int it = 0; it < 16; ++it) {
      int idx = tid + it * 256;
      int col = idx >> 6, k16 = idx & 63;
      uint4 v;
      if constexpr (std::is_same_v<BT, float>) {
        const float* src = Bn + (size_t)(n0 + col) * ldb + kc + k16 * 8;
        const float4 f0 = *reinterpret_cast<const float4*>(src);
        const float4 f1 = *reinterpret_cast<const float4*>(src + 4);
        v.x = (unsigned)f2bf(f0.x) | ((unsigned)f2bf(f0.y) << 16);
        v.y = (unsigned)f2bf(f0.z) | ((unsigned)f2bf(f0.w) << 16);
        v.z = (unsigned)f2bf(f1.x) | ((unsigned)f2bf(f1.y) << 16);
        v.w = (unsigned)f2bf(f1.z) | ((unsigned)f2bf(f1.w) << 16);
      } else {
        v = *reinterpret_cast<const uint4*>(Bn + (size_t)(n0 + col) * ldb + kc + k16 * 8);
      }
      int db = col * 1024 + ((k16 * 16) ^ ((col & 7) << 4));
      *reinterpret_cast<uint4*>(lds + db) = v;
    }
    __syncthreads();
    const AT* Arow = A + (size_t)(m0 + lr) * lda + kc + lg * 8;
#pragma unroll
    for (int ks = 0; ks < 16; ++ks) {
      bf16x8 af = ld_frag(Arow + ks * 32);
      int kb = ks * 64 + lg * 16;
#pragma unroll
      for (int f = 0; f < 4; ++f) {
        int col = f * 16 + lr;
        uint4 u = *reinterpret_cast<const uint4*>(lds + col * 1024 + (kb ^ ((col & 7) << 4)));
        acc[f] = mfma16(af, __builtin_bit_cast(bf16x8, u), acc[f]);
      }
    }
  }
#pragma unroll
  for (int f = 0; f < 4; ++f) {
    int cg = n0 + f * 16 + lr;
    float bv = bias ? bias[cg] : 0.f;
#pragma unroll
    for (int j = 0; j < 4; ++j) {
      int r = m0 + lg * 4 + j;
      float val = acc[f][j] + bv;
      if constexpr (std::is_same_v<DT, unsigned short>) D[(size_t)r * ldd + cg] = f2bf(val);
      else                                              D[(size_t)r * ldd + cg] = val;
    }
  }
}

// ---------------- persistent LSTM recurrence (direct-to-VGPR A) ----------
// mg = (bid&7)>>1, ng = (bid>>3)|((bid&1)<<5) (each XCD: one mg x 32 ngs ->
// A slice L2-shared). 8 waves = 8-way k-split: wave wk owns ALL 64 gate-cols
// x k-slice [wk*256, wk*256+256). B in registers (32 frags = 128 VGPR) for
// all 256 steps; acc 4x4 f32x4 (64 VGPR); A fragments loaded global->VGPR
// with a 2-kstep pipeline (32 VGPR window), no LDS, no barriers in the loop.
// LDS: 128KB dump for the 8-way k-reduce. Sync: round-10 slot-flag scheme.
__global__ __launch_bounds__(512, 2)
void k_lstm_p4(unsigned short* __restrict__ Ab0,
               unsigned short* __restrict__ Ab1,
               const unsigned short* __restrict__ Wg2,
               const float* __restrict__ bias0,
               const float* __restrict__ bias2,
               const float* __restrict__ cvec,
               float* __restrict__ hs,
               float* __restrict__ cs,
               unsigned* __restrict__ flags) {
  __shared__ char lds[131072];                      // 8 waves x 16KB dump
  const int tid = threadIdx.x;
  const int wave = tid >> 6, l = tid & 63;          // wave == wk (k-split)
  const int bid = blockIdx.x;
  const int mg = (bid & 7) >> 1;                    // XCD-pair-local
  const int ng = (bid >> 3) | ((bid & 1) << 5);
  const int lr = l & 15, lg = l >> 4;

  // ---- one-time: weight fragments -> registers (32 frags = 128 VGPR) ----
  // B[ks][in]: gate-col = in*16 + lr (in == gate index), k = wave*256 +
  // ks*32 + lg*8. grow = in*HID + ng*16 + lr.
  bf16x8 B[8][4];
#pragma unroll
  for (int ks = 0; ks < 8; ++ks)
#pragma unroll
    for (int in = 0; in < 4; ++in)
      B[ks][in] = ld_frag_bf(Wg2 + (size_t)(in * HID + ng * 16 + lr) * KDIM
                             + wave * 256 + ks * 32 + lg * 8);

  // ---- one-time: cell state + BOTH bias sets in registers ----
  const int m = tid >> 3;                           // batch row in WG
  const int hcp = tid & 7;
  const int b_row = mg * 64 + m;
  const int hid0 = ng * 16 + hcp * 2;
  float creg[2];
  {
    const float2 cv = *reinterpret_cast<const float2*>(cvec + (size_t)b_row * HID + hid0);
    creg[0] = cv.x; creg[1] = cv.y;
  }
  float b0r[2][4], b2r[2][4];
#pragma unroll
  for (int e = 0; e < 2; ++e)
#pragma unroll
    for (int g = 0; g < 4; ++g) {
      b0r[e][g] = bias0[g * HID + hid0 + e];
      b2r[e][g] = bias2[g * HID + hid0 + e];
    }

  for (int t = 0; t < SEQ; ++t) {
    const unsigned short* Acur = (t & 1) ? Ab1 : Ab0;
    unsigned short* Anxt = (t & 1) ? Ab0 : Ab1;

    if (t > 0) {
      // wait for the 64 producers of batch-group mg (slot flags, no RMW).
      if (wave == 0) {
        for (;;) {
          unsigned v = __hip_atomic_load(&flags[(mg << 6) + l],
                                         __ATOMIC_RELAXED, __HIP_MEMORY_SCOPE_AGENT);
          if (__all((int)(v >= (unsigned)t))) break;
          __builtin_amdgcn_s_sleep(0);
        }
        // one acquire -> inv (drops stale clean A lines in this CU/L2)
        (void)__hip_atomic_load(&flags[mg << 6], __ATOMIC_ACQUIRE,
                                __HIP_MEMORY_SCOPE_AGENT);
      }
      __syncthreads();   // A(t) visible; last step's reduce-LDS reads done
    }

    // ---- GEMM: A direct global->VGPR, 2-kstep pipeline, no barriers ----
    // a-frag (im, ks): rows mg*64 + im*16 + lr, k = wave*256 + ks*32 + lg*8
    const unsigned short* Arow =
        Acur + (size_t)(mg * 64 + lr) * KDIM + wave * 256 + lg * 8;
    bf16x8 a0[4], a1[4];
#pragma unroll
    for (int im = 0; im < 4; ++im) a0[im] = ld_frag_bf(Arow + im * 16 * KDIM);
#pragma unroll
    for (int im = 0; im < 4; ++im) a1[im] = ld_frag_bf(Arow + im * 16 * KDIM + 32);

    f32x4 acc[4][4] = {};
#pragma unroll
    for (int ks = 0; ks < 8; ++ks) {
#pragma unroll
      for (int im = 0; im < 4; ++im) {
        bf16x8 af = (ks & 1) ? a1[im] : a0[im];
#pragma unroll
        for (int in = 0; in < 4; ++in)
          acc[im][in] = mfma16(af, B[ks][in], acc[im][in]);
      }
      if (ks < 6) {
#pragma unroll
        for (int im = 0; im < 4; ++im) {
          bf16x8 nf = ld_frag_bf(Arow + im * 16 * KDIM + (ks + 2) * 32);
          if (ks & 1) a1[im] = nf; else a0[im] = nf;
        }
      }
    }

    // ---- dump all 16 partial frags: [wave][im*4+in][lane] ----
#pragma unroll
    for (int im = 0; im < 4; ++im)
#pragma unroll
      for (int in = 0; in < 4; ++in)
        *reinterpret_cast<f32x4*>(lds + wave * 16384 + (im * 4 + in) * 1024 + l * 16) =
            acc[im][in];
    __syncthreads();

    // ---- epilogue: 2 cells/thread, 8-way k-reduce from LDS ----
    float cn2[2], hn2[2];
#pragma unroll
    for (int e = 0; e < 2; ++e) {
      int hc = hcp * 2 + e;
      float pre[4];
#pragma unroll
      for (int g = 0; g < 4; ++g) {
        // partial for (row m, gate g, hid col hc) in wave w at:
        // frag = (m>>4)*4 + g, lane = ((m&15)>>2)*16 + hc, j = m&3
        int boff = (((m >> 4) << 2) + g) * 1024
                 + ((((m & 15) >> 2) << 4) + hc) * 16 + ((m & 3) << 2);
        float s = 0.f;
#pragma unroll
        for (int w8 = 0; w8 < 8; ++w8)
          s += *reinterpret_cast<const float*>(lds + w8 * 16384 + boff);
        pre[g] = s + ((t == 0) ? b0r[e][g] : b2r[e][g]);
      }
      float si = sigmoid_fast(pre[0]);
      float sf = sigmoid_fast(pre[1]);
      float so = sigmoid_fast(pre[3]);
      float tg = tanh_fast(pre[2]);
      float cn = sf * creg[e] + si * tg;
      float hn = so * tanh_fast(cn);
      creg[e] = cn;
      cn2[e] = cn;
      hn2[e] = hn;
    }
    // ---- EARLY PUBLISH: A-handoff stores (sc1 -> coherent point) first ----
    unsigned hpack = (unsigned)f2bf(hn2[0]) | ((unsigned)f2bf(hn2[1]) << 16);
    unsigned cpack = (unsigned)f2bf(cn2[0]) | ((unsigned)f2bf(cn2[1]) << 16);
    __hip_atomic_store(reinterpret_cast<unsigned*>(Anxt + (size_t)b_row * KDIM + hid0),
                       hpack, __ATOMIC_RELAXED, __HIP_MEMORY_SCOPE_AGENT);
    __hip_atomic_store(reinterpret_cast<unsigned*>(Anxt + (size_t)b_row * KDIM + HID + hid0),
                       cpack, __ATOMIC_RELAXED, __HIP_MEMORY_SCOPE_AGENT);
    asm volatile("s_waitcnt vmcnt(0)" ::: "memory");   // A stores at L3
    __builtin_amdgcn_s_barrier();                      // all waves drained
    if (tid == 0)
      __hip_atomic_store(&flags[(mg << 6) + ng], (unsigned)(t + 1),
                         __ATOMIC_RELAXED, __HIP_MEMORY_SCOPE_AGENT);
    // hs/cs stores AFTER publish: retire under the next step's poll.
    size_t o = (size_t)b_row * (SEQ * HID) + (size_t)t * HID + hid0;
    *reinterpret_cast<float2*>(hs + o) = make_float2(hn2[0], hn2[1]);
    *reinterpret_cast<float2*>(cs + o) = make_float2(cn2[0], cn2[1]);
  }
}

// ---------------- launch ----------------
extern "C" void kernel_launch(void* const* d_in, const int* in_sizes, int n_in,
                              void* d_out, int out_size, void* d_ws, size_t ws_size,
                              hipStream_t stream) {
  const float* c_vec = (const float*)d_in[0];
  const float* W_ih  = (const float*)d_in[1];
  const float* W_hh  = (const float*)d_in[2];
  const float* b_ih  = (const float*)d_in[3];
  const float* b_hh  = (const float*)d_in[4];
  const float* W_out = (const float*)d_in[5];
  const float* b_out = (const float*)d_in[6];

  float* out = (float*)d_out;
  float* hs = out;
  float* cs = out + (size_t)BATCH * SEQ * HID;
  float* os = out + (size_t)2 * BATCH * SEQ * HID;

  // Scratch in the `outs` region (134 MB; final GEMM reads nothing from it).
  char* sc = (char*)os;
  unsigned short* Wg2   = (unsigned short*)(sc);                 // 16 MB
  unsigned short* WoTT  = (unsigned short*)(sc + (16u << 20));   // 1 MB
  unsigned short* A0    = (unsigned short*)(sc + (17u << 20));   // 1 MB
  unsigned short* A1    = (unsigned short*)(sc + (18u << 20));   // 1 MB
  float*          bias0 = (float*)(sc + (19u << 20));
  float*          bias2 = (float*)(sc + (19u << 20) + 16384);
  unsigned*       g_flg = (unsigned*)(sc + (19u << 20) + 32768); // 256 uints

  k_cast_whh<<<dim3(GATES * HID / 4 / 256), dim3(256), 0, stream>>>(W_hh, Wg2);
  k_cast_wout<<<dim3(OUTD * HID / 256), dim3(256), 0, stream>>>(W_out, WoTT);
  k_init<<<dim3(BATCH * KDIM / 256), dim3(256), 0, stream>>>(c_vec, A0, g_flg);
  k_bias<<<dim3(GATES / 4), dim3(256), 0, stream>>>(W_ih, b_ih, b_hh, b_out, bias0, bias2);
  // Wc2 = W_ih @ W_out -> Wg2[:, 1024:2048]
  k_gemm<float, unsigned short, unsigned short>
      <<<dim3(HID / 64, GATES / 64), dim3(256), 0, stream>>>(
      W_ih, OUTD, WoTT, OUTD, Wg2 + HID, KDIM, (const float*)nullptr, OUTD);

  // persistent recurrence: all 256 steps in one cooperative kernel
  {
    void* args[] = {(void*)&A0, (void*)&A1, (void*)&Wg2, (void*)&bias0,
                    (void*)&bias2, (void*)&c_vec, (void*)&hs, (void*)&cs,
                    (void*)&g_flg};
    hipLaunchCooperativeKernel((const void*)k_lstm_p4, dim3(256), dim3(512),
                               args, 0, stream);
  }

  // outs = cs @ W_out^T + b_out  (M = 65536, N = 512, K = 1024)
  k_gemm<float, float, float>
      <<<dim3(OUTD / 64, BATCH * SEQ / 64), dim3(256), 0, stream>>>(
      cs, HID, W_out, HID, os, OUTD, b_out, HID);
}

// Round 12
// 2723.854 us; speedup vs baseline: 1.4752x; 1.4752x over previous
//
#include <hip/hip_runtime.h>
#include <cstdint>
#include <cstddef>
#include <type_traits>

// LSTM decoder: SEQ=256 steps, BATCH=256, HID=1024, OUT=512. f32 in/out.
// Folded recurrence (Wc2 = W_ih @ W_out): each step is ONE GEMM
//   gates = [h | c] @ [W_hh | Wc2]^T  (M=256, N=4096, K=2048, bf16 MFMA)
// Round-12: revert recurrence to the round-10 structure (proven 2340us:
// global_load_lds 8x32KB depth-3 staging, counted vmcnt, slot-flag sync,
// early publish, fast transcendentals) with ONE change: the k-reduce
// dump/read gets a +16*(l>>4) offset (stride 1088) that turns the 4-way
// reduce-read bank conflict into a free 2-way. Final GEMM gets a BN=128
// tile (k_gemm<F=8,KC=256>); the Wc2 GEMM keeps the proven F=4/KC=512 path.
// Scratch lives in the `outs` third of d_out; d_ws unused.

#define SEQ    256
#define BATCH  256
#define HID    1024
#define OUTD   512
#define KDIM   2048
#define GATES  4096

typedef __bf16 bf16x8 __attribute__((ext_vector_type(8)));
typedef float  f32x4  __attribute__((ext_vector_type(4)));

__device__ __forceinline__ unsigned short f2bf(float x) {
  unsigned u = __float_as_uint(x);
  u = (u + 0x7FFFu + ((u >> 16) & 1u)) >> 16;   // RNE
  return (unsigned short)u;
}

__device__ __forceinline__ f32x4 mfma16(bf16x8 a, bf16x8 b, f32x4 c) {
  return __builtin_amdgcn_mfma_f32_16x16x32_bf16(a, b, c, 0, 0, 0);
}

__device__ __forceinline__ bf16x8 ld_frag_bf(const unsigned short* p) {
  uint4 u = *reinterpret_cast<const uint4*>(p);
  return __builtin_bit_cast(bf16x8, u);
}

__device__ __forceinline__ float rcp_fast(float x) {
  float r;
  asm("v_rcp_f32 %0, %1" : "=v"(r) : "v"(x));
  return r;
}
__device__ __forceinline__ float sigmoid_fast(float x) {
  return rcp_fast(1.f + __expf(-x));
}
__device__ __forceinline__ float tanh_fast(float x) {
  float xc = fminf(fmaxf(x, -15.f), 15.f);     // e^{2x} finite; tanh saturated
  float e2 = __expf(2.f * xc);
  return 1.f - 2.f * rcp_fast(1.f + e2);
}

#define GLOAD_LDS16(gp, lp)                                                   \
  __builtin_amdgcn_global_load_lds(                                           \
      (const __attribute__((address_space(1))) unsigned int*)(gp),            \
      (__attribute__((address_space(3))) unsigned int*)(lp), 16, 0, 0)

// ---------------- prep kernels ----------------

__global__ void k_cast_whh(const float* __restrict__ whh, unsigned short* __restrict__ wg2) {
  int i4 = blockIdx.x * blockDim.x + threadIdx.x;
  if (i4 >= (GATES * HID) / 4) return;
  int idx = i4 * 4;
  int n = idx >> 10, k = idx & 1023;
  const float4 v = *reinterpret_cast<const float4*>(whh + idx);
  ushort4 o; o.x = f2bf(v.x); o.y = f2bf(v.y); o.z = f2bf(v.z); o.w = f2bf(v.w);
  *reinterpret_cast<ushort4*>(wg2 + (size_t)n * KDIM + k) = o;
}

__global__ void k_cast_wout(const float* __restrict__ wout,
                            unsigned short* __restrict__ wott) {
  int idx = blockIdx.x * blockDim.x + threadIdx.x;
  if (idx >= OUTD * HID) return;
  int j = idx >> 10, k = idx & 1023;
  wott[(size_t)k * OUTD + j] = f2bf(wout[idx]);
}

// A0 = [bf16(c_vector) | 0]; zero the 256 per-WG step flags (every launch,
// for graph-replay determinism).
__global__ void k_init(const float* __restrict__ cvec,
                       unsigned short* __restrict__ a0,
                       unsigned* __restrict__ flags) {
  int idx = blockIdx.x * blockDim.x + threadIdx.x;
  if (idx < 256) flags[idx] = 0u;
  if (idx >= BATCH * KDIM) return;
  int b = idx >> 11, k = idx & 2047;
  a0[idx] = (k < HID) ? f2bf(cvec[(size_t)b * HID + k]) : (unsigned short)0;
}

// bias0[n] = b_ih+b_hh ; bias2[n] = bias0[n] + dot(W_ih[n,:], b_out)
__global__ void k_bias(const float* __restrict__ wih, const float* __restrict__ b_ih,
                       const float* __restrict__ b_hh, const float* __restrict__ b_out,
                       float* __restrict__ bias0, float* __restrict__ bias2) {
  int wave = threadIdx.x >> 6, l = threadIdx.x & 63;
  int n = blockIdx.x * 4 + wave;
  float s = 0.f;
  for (int j = l; j < OUTD; j += 64) s += wih[(size_t)n * OUTD + j] * b_out[j];
  for (int off = 32; off; off >>= 1) s += __shfl_down(s, off);
  if (l == 0) {
    float b0 = b_ih[n] + b_hh[n];
    bias0[n] = b0;
    bias2[n] = b0 + s;
  }
}

// ---------------- generic bf16-MFMA GEMM (templated tile) ----------------
// F = n-frags per wave (BN = F*16), KC = k-chunk. <4,512> is byte-identical
// to the proven round-10 path; <8,256> is the wide final-GEMM tile (same
// 64KB LDS, 2 blocks/CU, 2x MFMA per staged byte, 4x less A re-read).
template <typename AT>
__device__ __forceinline__ bf16x8 ld_frag(const AT* p) {
  if constexpr (std::is_same_v<AT, float>) {
    const float4 f0 = *reinterpret_cast<const float4*>(p);
    const float4 f1 = *reinterpret_cast<const float4*>(p + 4);
    uint4 v;
    v.x = (unsigned)f2bf(f0.x) | ((unsigned)f2bf(f0.y) << 16);
    v.y = (unsigned)f2bf(f0.z) | ((unsigned)f2bf(f0.w) << 16);
    v.z = (unsigned)f2bf(f1.x) | ((unsigned)f2bf(f1.y) << 16);
    v.w = (unsigned)f2bf(f1.z) | ((unsigned)f2bf(f1.w) << 16);
    return __builtin_bit_cast(bf16x8, v);
  } else {
    return ld_frag_bf(p);
  }
}

template <typename AT, typename BT, typename DT, int F, int KC>
__global__ __launch_bounds__(256)
void k_gemm(const AT* __restrict__ A, int lda,
            const BT* __restrict__ Bn, int ldb,
            DT* __restrict__ D, int ldd,
            const float* __restrict__ bias, int K) {
  __shared__ char lds[F * 16 * KC * 2];
  const int tid = threadIdx.x;
  const int w = tid >> 6, l = tid & 63;
  const int n0 = blockIdx.x * (F * 16);
  const int m0 = blockIdx.y * 64 + w * 16;
  const int lr = l & 15, lg = l >> 4;

  f32x4 acc[F] = {};
  for (int kc = 0; kc < K; kc += KC) {
    __syncthreads();
#pragma unroll
    for (int it = 0; it < (F * 16 * (KC / 8)) / 256; ++it) {
      int idx = tid + it * 256;
      int col = idx / (KC / 8), k16 = idx % (KC / 8);
      uint4 v;
      if constexpr (std::is_same_v<BT, float>) {
        const float* src = Bn + (size_t)(n0 + col) * ldb + kc + k16 * 8;
        const float4 f0 = *reinterpret_cast<const float4*>(src);
        const float4 f1 = *reinterpret_cast<const float4*>(src + 4);
        v.x = (unsigned)f2bf(f0.x) | ((unsigned)f2bf(f0.y) << 16);
        v.y = (unsigned)f2bf(f0.z) | ((unsigned)f2bf(f0.w) << 16);
        v.z = (unsigned)f2bf(f1.x) | ((unsigned)f2bf(f1.y) << 16);
        v.w = (unsigned)f2bf(f1.z) | ((unsigned)f2bf(f1.w) << 16);
      } else {
        v = *reinterpret_cast<const uint4*>(Bn + (size_t)(n0 + col) * ldb + kc + k16 * 8);
      }
      int db = col * (KC * 2) + ((k16 * 16) ^ ((col & 7) << 4));
      *reinterpret_cast<uint4*>(lds + db) = v;
    }
    __syncthreads();
    const AT* Arow = A + (size_t)(m0 + lr) * lda + kc + lg * 8;
#pragma unroll
    for (int ks = 0; ks < KC / 32; ++ks) {
      bf16x8 af = ld_frag(Arow + ks * 32);
      int kb = ks * 64 + lg * 16;
#pragma unroll
      for (int f = 0; f < F; ++f) {
        int col = f * 16 + lr;
        uint4 u = *reinterpret_cast<const uint4*>(
            lds + col * (KC * 2) + (kb ^ ((col & 7) << 4)));
        acc[f] = mfma16(af, __builtin_bit_cast(bf16x8, u), acc[f]);
      }
    }
  }
#pragma unroll
  for (int f = 0; f < F; ++f) {
    int cg = n0 + f * 16 + lr;
    float bv = bias ? bias[cg] : 0.f;
#pragma unroll
    for (int j = 0; j < 4; ++j) {
      int r = m0 + lg * 4 + j;
      float val = acc[f][j] + bv;
      if constexpr (std::is_same_v<DT, unsigned short>) D[(size_t)r * ldd + cg] = f2bf(val);
      else                                              D[(size_t)r * ldd + cg] = val;
    }
  }
}

// ---------------- persistent LSTM recurrence (round-10 structure) ---------
// mg = (bid&7)>>1 (XCD pair-local batch group, 64 rows), ng = (bid>>3) |
// ((bid&1)<<5) (16 hid cols = 64 gate rows). Waves: wn = wave>>2 (32 gate
// cols), wk = wave&3 (k-split 4). B-frags in registers for ALL 256 steps.
// A staged in 8 chunks of 32KB, 4 buffers, depth-3 prefetch, counted vmcnt.
// Dump/reduce use stride 1088 + a +16*(l>>4) offset: reduce-read bank
// conflict drops 4-way -> 2-way (free per m136).
__global__ __launch_bounds__(512, 2)
void k_lstm_p5(unsigned short* __restrict__ Ab0,
               unsigned short* __restrict__ Ab1,
               const unsigned short* __restrict__ Wg2,
               const float* __restrict__ bias0,
               const float* __restrict__ bias2,
               const float* __restrict__ cvec,
               float* __restrict__ hs,
               float* __restrict__ cs,
               unsigned* __restrict__ flags) {
  __shared__ char lds[131072];                      // 4 x 32KB chunk buffers
  const int tid = threadIdx.x;
  const int wave = tid >> 6, l = tid & 63;
  const int wn = wave >> 2, wk = wave & 3;
  const int bid = blockIdx.x;
  const int mg = (bid & 7) >> 1;                    // XCD-pair-local
  const int ng = (bid >> 3) | ((bid & 1) << 5);
  const int lr = l & 15, lg = l >> 4;

  // ---- one-time: weight fragments -> registers (32 frags = 128 VGPR) ----
  bf16x8 B[8][2][2];   // [chunk][ks][in]
#pragma unroll
  for (int c = 0; c < 8; ++c)
#pragma unroll
    for (int ks = 0; ks < 2; ++ks)
#pragma unroll
      for (int in = 0; in < 2; ++in) {
        int col = wn * 32 + in * 16 + lr;                  // WG gate-col 0..63
        int grow = (col >> 4) * HID + ng * 16 + (col & 15);
        int kb = c * 256 + wk * 64 + ks * 32 + lg * 8;
        B[c][ks][in] = ld_frag_bf(Wg2 + (size_t)grow * KDIM + kb);
      }

  // ---- one-time: cell state + BOTH bias sets in registers ----
  const int m = tid >> 3;                           // batch row in WG
  const int hcp = tid & 7;
  const int b_row = mg * 64 + m;
  const int hid0 = ng * 16 + hcp * 2;
  float creg[2];
  {
    const float2 cv = *reinterpret_cast<const float2*>(cvec + (size_t)b_row * HID + hid0);
    creg[0] = cv.x; creg[1] = cv.y;
  }
  float b0r[2][4], b2r[2][4];
#pragma unroll
  for (int e = 0; e < 2; ++e)
#pragma unroll
    for (int g = 0; g < 4; ++g) {
      b0r[e][g] = bias0[g * HID + hid0 + e];
      b2r[e][g] = bias2[g * HID + hid0 + e];
    }
  // one-time drain: B/bias/cvec loads retired before the step loop.
  asm volatile("s_waitcnt vmcnt(0)" ::: "memory");

  for (int t = 0; t < SEQ; ++t) {
    const unsigned short* Acur = (t & 1) ? Ab1 : Ab0;
    unsigned short* Anxt = (t & 1) ? Ab0 : Ab1;

    if (t > 0) {
      // wait for the 64 producers of batch-group mg (slot flags, no RMW).
      if (wave == 0) {
        for (;;) {
          unsigned v = __hip_atomic_load(&flags[(mg << 6) + l],
                                         __ATOMIC_RELAXED, __HIP_MEMORY_SCOPE_AGENT);
          if (__all((int)(v >= (unsigned)t))) break;
          __builtin_amdgcn_s_sleep(0);
        }
        // one acquire -> inv (drops stale clean A lines in this L2)
        (void)__hip_atomic_load(&flags[mg << 6], __ATOMIC_ACQUIRE,
                                __HIP_MEMORY_SCOPE_AGENT);
      }
      __syncthreads();   // A(t) visible; last step's reduce-LDS reads done
    }

    // stage chunk c of A (64 rows x 256 k bf16 = 32KB) into LDS buffer.
    auto STAGE = [&](int buf, int c) {
      const unsigned short* base = Acur + (size_t)(mg * 64) * KDIM + c * 256;
#pragma unroll
      for (int it = 0; it < 4; ++it) {
        int s_lin = it * 512 + tid;
        int row = s_lin >> 5, slot = s_lin & 31;
        const unsigned short* g = base + (size_t)row * KDIM + ((slot ^ (row & 7)) * 8);
        GLOAD_LDS16(g, lds + buf * 32768 + s_lin * 16);
      }
    };

    STAGE(0, 0);
    STAGE(1, 1);
    STAGE(2, 2);

    f32x4 acc[4][2] = {};
#pragma unroll
    for (int c = 0; c < 8; ++c) {
      // FIFO (stage ops + the <=3 early-retiring stores from last step):
      // c<=5: {c,c+1,c+2} in flight -> vmcnt(8); c==6: {6,7} -> vmcnt(4);
      // c==7: {7} -> vmcnt(0).
      if (c <= 5)      { asm volatile("s_waitcnt vmcnt(8)" ::: "memory"); }
      else if (c == 6) { asm volatile("s_waitcnt vmcnt(4)" ::: "memory"); }
      else             { asm volatile("s_waitcnt vmcnt(0)" ::: "memory"); }
      __builtin_amdgcn_s_barrier();
      const char* buf = lds + (c & 3) * 32768;
#pragma unroll
      for (int ks = 0; ks < 2; ++ks) {
        bf16x8 a[4];
#pragma unroll
        for (int im = 0; im < 4; ++im) {
          int row = im * 16 + lr;
          int k16 = wk * 8 + ks * 4 + lg;             // 16B slot in chunk row
          a[im] = *reinterpret_cast<const bf16x8*>(
              buf + row * 512 + ((k16 ^ (row & 7)) << 4));
        }
#pragma unroll
        for (int im = 0; im < 4; ++im)
#pragma unroll
          for (int in = 0; in < 2; ++in)
            acc[im][in] = mfma16(a[im], B[c][ks][in], acc[im][in]);
      }
      if (c <= 4) STAGE((c + 3) & 3, c + 3);
    }

    // ---- all phase-7 reads done -> dump partials (stride 1088, +16*lg
    // lane offset: reduce-read conflicts 4-way -> 2-way) ----
    asm volatile("" ::: "memory");
    __builtin_amdgcn_s_barrier();
#pragma unroll
    for (int im = 0; im < 4; ++im)
#pragma unroll
      for (int in = 0; in < 2; ++in)
        *reinterpret_cast<f32x4*>(lds + wave * 8704 + (im * 2 + in) * 1088
                                  + l * 16 + (l >> 4) * 16) = acc[im][in];
    __syncthreads();

    // ---- epilogue: 2 consecutive cells/thread, 4-way k-reduce from LDS ----
    float cn2[2], hn2[2];
#pragma unroll
    for (int e = 0; e < 2; ++e) {
      int hc = hcp * 2 + e;
      float pre[4];
#pragma unroll
      for (int g = 0; g < 4; ++g) {
        int n = g * 16 + hc;                               // WG gate-col
        int wn_r = n >> 5, nn = n & 31;
        int frag = ((m >> 4) << 1) | (nn >> 4);
        int lane_r = ((m & 15) >> 2) * 16 + (nn & 15);
        int j = m & 3;
        float s = 0.f;
#pragma unroll
        for (int wkk = 0; wkk < 4; ++wkk)
          s += *reinterpret_cast<const float*>(
              lds + (wn_r * 4 + wkk) * 8704 + frag * 1088
              + lane_r * 16 + ((m & 15) >> 2) * 16 + j * 4);
        pre[g] = s + ((t == 0) ? b0r[e][g] : b2r[e][g]);
      }
      float si = sigmoid_fast(pre[0]);
      float sf = sigmoid_fast(pre[1]);
      float so = sigmoid_fast(pre[3]);
      float tg = tanh_fast(pre[2]);
      float cn = sf * creg[e] + si * tg;
      float hn = so * tanh_fast(cn);
      creg[e] = cn;
      cn2[e] = cn;
      hn2[e] = hn;
    }
    // ---- EARLY PUBLISH: A-handoff stores (sc1 -> coherent point) first ----
    unsigned hpack = (unsigned)f2bf(hn2[0]) | ((unsigned)f2bf(hn2[1]) << 16);
    unsigned cpack = (unsigned)f2bf(cn2[0]) | ((unsigned)f2bf(cn2[1]) << 16);
    __hip_atomic_store(reinterpret_cast<unsigned*>(Anxt + (size_t)b_row * KDIM + hid0),
                       hpack, __ATOMIC_RELAXED, __HIP_MEMORY_SCOPE_AGENT);
    __hip_atomic_store(reinterpret_cast<unsigned*>(Anxt + (size_t)b_row * KDIM + HID + hid0),
                       cpack, __ATOMIC_RELAXED, __HIP_MEMORY_SCOPE_AGENT);
    asm volatile("s_waitcnt vmcnt(0)" ::: "memory");   // A stores at L3
    __builtin_amdgcn_s_barrier();                      // all waves drained
    if (tid == 0)
      __hip_atomic_store(&flags[(mg << 6) + ng], (unsigned)(t + 1),
                         __ATOMIC_RELAXED, __HIP_MEMORY_SCOPE_AGENT);
    // hs/cs stores AFTER publish: retire under the next step's poll/stage
    // (accounted in the phase-0 vmcnt(8): they are the oldest FIFO entries).
    size_t o = (size_t)b_row * (SEQ * HID) + (size_t)t * HID + hid0;
    *reinterpret_cast<float2*>(hs + o) = make_float2(hn2[0], hn2[1]);
    *reinterpret_cast<float2*>(cs + o) = make_float2(cn2[0], cn2[1]);
  }
}

// ---------------- launch ----------------
extern "C" void kernel_launch(void* const* d_in, const int* in_sizes, int n_in,
                              void* d_out, int out_size, void* d_ws, size_t ws_size,
                              hipStream_t stream) {
  const float* c_vec = (const float*)d_in[0];
  const float* W_ih  = (const float*)d_in[1];
  const float* W_hh  = (const float*)d_in[2];
  const float* b_ih  = (const float*)d_in[3];
  const float* b_hh  = (const float*)d_in[4];
  const float* W_out = (const float*)d_in[5];
  const float* b_out = (const float*)d_in[6];

  float* out = (float*)d_out;
  float* hs = out;
  float* cs = out + (size_t)BATCH * SEQ * HID;
  float* os = out + (size_t)2 * BATCH * SEQ * HID;

  // Scratch in the `outs` region (134 MB; final GEMM reads nothing from it).
  char* sc = (char*)os;
  unsigned short* Wg2   = (unsigned short*)(sc);                 // 16 MB
  unsigned short* WoTT  = (unsigned short*)(sc + (16u << 20));   // 1 MB
  unsigned short* A0    = (unsigned short*)(sc + (17u << 20));   // 1 MB
  unsigned short* A1    = (unsigned short*)(sc + (18u << 20));   // 1 MB
  float*          bias0 = (float*)(sc + (19u << 20));
  float*          bias2 = (float*)(sc + (19u << 20) + 16384);
  unsigned*       g_flg = (unsigned*)(sc + (19u << 20) + 32768); // 256 uints

  k_cast_whh<<<dim3(GATES * HID / 4 / 256), dim3(256), 0, stream>>>(W_hh, Wg2);
  k_cast_wout<<<dim3(OUTD * HID / 256), dim3(256), 0, stream>>>(W_out, WoTT);
  k_init<<<dim3(BATCH * KDIM / 256), dim3(256), 0, stream>>>(c_vec, A0, g_flg);
  k_bias<<<dim3(GATES / 4), dim3(256), 0, stream>>>(W_ih, b_ih, b_hh, b_out, bias0, bias2);
  // Wc2 = W_ih @ W_out -> Wg2[:, 1024:2048]  (proven F=4/KC=512 path)
  k_gemm<float, unsigned short, unsigned short, 4, 512>
      <<<dim3(HID / 64, GATES / 64), dim3(256), 0, stream>>>(
      W_ih, OUTD, WoTT, OUTD, Wg2 + HID, KDIM, (const float*)nullptr, OUTD);

  // persistent recurrence: all 256 steps in one cooperative kernel
  {
    void* args[] = {(void*)&A0, (void*)&A1, (void*)&Wg2, (void*)&bias0,
                    (void*)&bias2, (void*)&c_vec, (void*)&hs, (void*)&cs,
                    (void*)&g_flg};
    hipLaunchCooperativeKernel((const void*)k_lstm_p5, dim3(256), dim3(512),
                               args, 0, stream);
  }

  // outs = cs @ W_out^T + b_out  (M = 65536, N = 512, K = 1024)
  // BN=128 tile: 4x less A-panel re-read, 2x MFMA per staged byte.
  k_gemm<float, float, float, 8, 256>
      <<<dim3(OUTD / 128, BATCH * SEQ / 64), dim3(256), 0, stream>>>(
      cs, HID, W_out, HID, os, OUTD, b_out, HID);
}